// Round 1
// 202.935 us; speedup vs baseline: 1.0228x; 1.0228x over previous
//
#include <hip/hip_runtime.h>

// Problem constants (match reference.py)
#define BB 64
#define SS 512
#define WW 400
#define DD 1024
#define D4 (DD / 4)        // 256 float4 per row
#define NBW (BB * WW)      // 25600 spans

typedef float f32x4 __attribute__((ext_vector_type(4)));

// Wave-per-span: each 64-lane wave owns one (b,w) span.
// Lane l owns float4 chunks l, l+64, l+128, l+192 of the D dimension
// -> 4 independent accumulators, 4 outstanding 1KB loads per row,
//    8 outstanding with the 2-row unroll.
// Persistent grid-stride with next-span metadata prefetch.
__global__ __launch_bounds__(256) void bert_span_mean(
    const float* __restrict__ emb,     // [B, S, D]
    const int*   __restrict__ offs,    // [B, W, 2]
    const int*   __restrict__ mask,    // [B, W]
    float*       __restrict__ out)     // [B, W, D]
{
    const int lane = threadIdx.x & 63;
    const int wid  = threadIdx.x >> 6;          // wave id in block: 0..3
    const int nw   = gridDim.x << 2;            // total waves in grid

    const int2* __restrict__ offs2 = reinterpret_cast<const int2*>(offs);

    int bw = (blockIdx.x << 2) + wid;
    if (bw >= NBW) return;

    // metadata for current span
    int2 se = offs2[bw];
    int  m  = mask[bw];

    while (true) {
        // ---- prefetch next span's metadata before the row loop ----
        const int bwn = bw + nw;
        int2 sen = make_int2(0, 0);
        int  mn  = 0;
        if (bwn < NBW) {
            sen = offs2[bwn];
            mn  = mask[bwn];
        }

        const int st = se.x;
        const int ed = se.y;
        const int b  = bw / WW;

        f32x4 a0 = {0.f, 0.f, 0.f, 0.f};
        f32x4 a1 = a0, a2 = a0, a3 = a0;

        if (m != 0 && ed > st) {
            const f32x4* __restrict__ src = reinterpret_cast<const f32x4*>(
                emb + (size_t)b * (SS * DD)) + lane;
            int s = st;
            // 2-row unroll: 8 loads in flight, adds stay in ascending-s
            // order per element (bitwise match with reference).
            for (; s + 2 <= ed; s += 2) {
                const f32x4* r0 = src + (size_t)s * D4;
                const f32x4* r1 = r0 + D4;
                f32x4 v0 = __builtin_nontemporal_load(r0);
                f32x4 v1 = __builtin_nontemporal_load(r0 + 64);
                f32x4 v2 = __builtin_nontemporal_load(r0 + 128);
                f32x4 v3 = __builtin_nontemporal_load(r0 + 192);
                f32x4 w0 = __builtin_nontemporal_load(r1);
                f32x4 w1 = __builtin_nontemporal_load(r1 + 64);
                f32x4 w2 = __builtin_nontemporal_load(r1 + 128);
                f32x4 w3 = __builtin_nontemporal_load(r1 + 192);
                a0 += v0; a1 += v1; a2 += v2; a3 += v3;
                a0 += w0; a1 += w1; a2 += w2; a3 += w3;
            }
            if (s < ed) {
                const f32x4* r0 = src + (size_t)s * D4;
                f32x4 v0 = __builtin_nontemporal_load(r0);
                f32x4 v1 = __builtin_nontemporal_load(r0 + 64);
                f32x4 v2 = __builtin_nontemporal_load(r0 + 128);
                f32x4 v3 = __builtin_nontemporal_load(r0 + 192);
                a0 += v0; a1 += v1; a2 += v2; a3 += v3;
            }
            const float inv = 1.0f / (float)(ed - st);
            a0 *= inv; a1 *= inv; a2 *= inv; a3 *= inv;
        }

        f32x4* __restrict__ dst =
            reinterpret_cast<f32x4*>(out) + (size_t)bw * D4 + lane;
        __builtin_nontemporal_store(a0, dst);
        __builtin_nontemporal_store(a1, dst + 64);
        __builtin_nontemporal_store(a2, dst + 128);
        __builtin_nontemporal_store(a3, dst + 192);

        if (bwn >= NBW) break;
        bw = bwn;
        se = sen;
        m  = mn;
    }
}

extern "C" void kernel_launch(void* const* d_in, const int* in_sizes, int n_in,
                              void* d_out, int out_size, void* d_ws, size_t ws_size,
                              hipStream_t stream) {
    const float* emb  = (const float*)d_in[0];
    const int*   offs = (const int*)d_in[1];
    const int*   mask = (const int*)d_in[2];
    float*       out  = (float*)d_out;

    // Persistent: 8 blocks/CU x 256 CUs; each block carries 4 waves,
    // each wave grid-strides over spans (25600 / 8192 waves ~ 3 spans).
    const int nblocks = 2048;
    bert_span_mean<<<nblocks, 256, 0, stream>>>(emb, offs, mask, out);
}

// Round 4
// 202.674 us; speedup vs baseline: 1.0241x; 1.0013x over previous
//
#include <hip/hip_runtime.h>

// Problem constants (match reference.py)
#define BB 64
#define SS 512
#define WW 400
#define DD 1024
#define D4 (DD / 4)        // 256 float4 per row
#define NBW (BB * WW)      // 25600 spans

typedef float f32x4 __attribute__((ext_vector_type(4)));

// Wave-per-span: each 64-lane wave owns one (b,w) span.
// Lane l owns float4 chunks l, l+64, l+128, l+192 of the D dimension
// -> 4 independent accumulators, 4 outstanding 1KB loads per row,
//    8 outstanding with the 2-row unroll.
// Persistent grid-stride with next-span metadata prefetch.
// Grid: 1600 blocks x 4 waves = 6400 waves -> exactly 4 spans/wave
// (perfect balance, no 3-vs-4 tail).
__global__ __launch_bounds__(256) void bert_span_mean(
    const float* __restrict__ emb,     // [B, S, D]
    const int*   __restrict__ offs,    // [B, W, 2]
    const int*   __restrict__ mask,    // [B, W]
    float*       __restrict__ out)     // [B, W, D]
{
    const int lane = threadIdx.x & 63;
    const int wid  = threadIdx.x >> 6;          // wave id in block: 0..3
    const int nw   = gridDim.x << 2;            // total waves in grid

    const int2* __restrict__ offs2 = reinterpret_cast<const int2*>(offs);

    int bw = (blockIdx.x << 2) + wid;
    if (bw >= NBW) return;

    // metadata for current span
    int2 se = offs2[bw];
    int  m  = mask[bw];

    while (true) {
        // ---- prefetch next span's metadata before the row loop ----
        const int bwn = bw + nw;
        int2 sen = make_int2(0, 0);
        int  mn  = 0;
        if (bwn < NBW) {
            sen = offs2[bwn];
            mn  = mask[bwn];
        }

        const int st = se.x;
        const int ed = se.y;
        const int b  = bw / WW;

        f32x4 a0 = {0.f, 0.f, 0.f, 0.f};
        f32x4 a1 = a0, a2 = a0, a3 = a0;

        if (m != 0 && ed > st) {
            const f32x4* __restrict__ src = reinterpret_cast<const f32x4*>(
                emb + (size_t)b * (SS * DD)) + lane;
            int s = st;
            // 2-row unroll: 8 loads in flight, adds stay in ascending-s
            // order per element (bitwise match with reference).
            for (; s + 2 <= ed; s += 2) {
                const f32x4* r0 = src + (size_t)s * D4;
                const f32x4* r1 = r0 + D4;
                f32x4 v0 = __builtin_nontemporal_load(r0);
                f32x4 v1 = __builtin_nontemporal_load(r0 + 64);
                f32x4 v2 = __builtin_nontemporal_load(r0 + 128);
                f32x4 v3 = __builtin_nontemporal_load(r0 + 192);
                f32x4 w0 = __builtin_nontemporal_load(r1);
                f32x4 w1 = __builtin_nontemporal_load(r1 + 64);
                f32x4 w2 = __builtin_nontemporal_load(r1 + 128);
                f32x4 w3 = __builtin_nontemporal_load(r1 + 192);
                a0 += v0; a1 += v1; a2 += v2; a3 += v3;
                a0 += w0; a1 += w1; a2 += w2; a3 += w3;
            }
            if (s < ed) {
                const f32x4* r0 = src + (size_t)s * D4;
                f32x4 v0 = __builtin_nontemporal_load(r0);
                f32x4 v1 = __builtin_nontemporal_load(r0 + 64);
                f32x4 v2 = __builtin_nontemporal_load(r0 + 128);
                f32x4 v3 = __builtin_nontemporal_load(r0 + 192);
                a0 += v0; a1 += v1; a2 += v2; a3 += v3;
            }
            const float inv = 1.0f / (float)(ed - st);
            a0 *= inv; a1 *= inv; a2 *= inv; a3 *= inv;
        }

        f32x4* __restrict__ dst =
            reinterpret_cast<f32x4*>(out) + (size_t)bw * D4 + lane;
        __builtin_nontemporal_store(a0, dst);
        __builtin_nontemporal_store(a1, dst + 64);
        __builtin_nontemporal_store(a2, dst + 128);
        __builtin_nontemporal_store(a3, dst + 192);

        if (bwn >= NBW) break;
        bw = bwn;
        se = sen;
        m  = mn;
    }
}

extern "C" void kernel_launch(void* const* d_in, const int* in_sizes, int n_in,
                              void* d_out, int out_size, void* d_ws, size_t ws_size,
                              hipStream_t stream) {
    const float* emb  = (const float*)d_in[0];
    const int*   offs = (const int*)d_in[1];
    const int*   mask = (const int*)d_in[2];
    float*       out  = (float*)d_out;

    // 1600 blocks x 4 waves = 6400 waves: exactly 4 spans per wave.
    const int nblocks = 1600;
    bert_span_mean<<<nblocks, 256, 0, stream>>>(emb, offs, mask, out);
}